// Round 13
// baseline (163.690 us; speedup 1.0000x reference)
//
#include <hip/hip_runtime.h>
#include <hip/hip_fp16.h>

#define HEADS 4
#define DH    32
#define HW    4096
#define CIN   256
#define HID   128
#define KSPLIT 2
#define KHALF (HW / KSPLIT)
#define NIT   (KHALF / 64)

using half8    = __attribute__((ext_vector_type(8))) _Float16;
using half4    = __attribute__((ext_vector_type(4))) _Float16;
using half2v   = __attribute__((ext_vector_type(2))) _Float16;
using floatx4  = __attribute__((ext_vector_type(4))) float;
using floatx16 = __attribute__((ext_vector_type(16))) float;
using uint4v   = __attribute__((ext_vector_type(4))) unsigned;

// P = exp2(s_log2 - 3*log2e); log2(e) folded into Q pre-scale, shift folded
// into the S-MFMA C-initializer. Fixed shift (no running max) => split-K
// partials combine by pure addition.
#define SHIFT2 4.328085122666891f
#define WQSCALE 0.25508275947f   // 32^-0.5 * log2(e)

static __device__ __forceinline__ unsigned pkr(float a, float b) {
  return __builtin_bit_cast(unsigned, __builtin_amdgcn_cvt_pkrtz(a, b));
}

// ---------------------------------------------------------------------------
// qkv_fused v4: THIS ROUND — zero LDS, zero barriers. The B-fragment
// (x^T slice) is loaded DIRECTLY from global: for fixed (ks,ns,j) lanes
// lm=0..15 read 16 consecutive floats (64B segment), quad spans 4 rows ->
// 4 segments/instr, L1/L2-hot (vs R4's 16-segment V-gather). A-fragments
// from L2-resident w as in R12. The f32 transpose tile, its 16 scalar
// stride-65 LDS reads/thread, Bs staging, and both barriers are deleted.
// p-tile 32 -> grid (2, 512) = 1024 blocks = 4 blocks/CU (was 2) for
// latency hiding; waves free-run. x HBM traffic unchanged (2x, L1 absorbs
// the intra-block 4-wave fragment duplication).
// ---------------------------------------------------------------------------
__global__ __launch_bounds__(256) void qkv_fused(
    const float* __restrict__ w, const float* __restrict__ x,
    _Float16* __restrict__ Qw, _Float16* __restrict__ Kw,
    _Float16* __restrict__ Vtw)
{
  const int mg = blockIdx.x, nt = blockIdx.y;
  const int b = nt >> 7, p0 = (nt & 127) * 32;
  const int tid = threadIdx.x;
  const int wv = tid >> 6, lane = tid & 63, lm = lane & 15, quad = lane >> 4;

  const float* xb = x + (size_t)b * CIN * HW + p0;

  floatx4 acc[3][2] = {{{0,0,0,0},{0,0,0,0}},
                       {{0,0,0,0},{0,0,0,0}},
                       {{0,0,0,0},{0,0,0,0}}};

  for (int kq = 0; kq < 4; ++kq) {
    // build 4 B-fragments straight from x (c = kq*64 + ks*32 + quad*8 + j)
    half8 bfr[2][2];
    #pragma unroll
    for (int ks = 0; ks < 2; ++ks)
      #pragma unroll
      for (int ns = 0; ns < 2; ++ns) {
        const float* src =
            xb + (size_t)(kq * 64 + ks * 32 + quad * 8) * HW + ns * 16 + lm;
        half8 bf;
        #pragma unroll
        for (int j = 0; j < 8; ++j)
          bf[j] = (_Float16)src[(size_t)j * HW];
        bfr[ks][ns] = bf;
      }

    #pragma unroll
    for (int im = 0; im < 3; ++im) {
      const int mt = mg * 3 + im;
      const float wscale = (mt < 2) ? WQSCALE : 1.0f;
      const float* Ag = w + (size_t)(mt * 64 + wv * 16 + lm) * CIN + kq * 64;
      #pragma unroll
      for (int ks = 0; ks < 2; ++ks) {
        const float* srcA = Ag + ks * 32 + quad * 8;
        float4 u0 = *(const float4*)(srcA);
        float4 u1 = *(const float4*)(srcA + 4);
        half8 a = {(_Float16)(u0.x * wscale), (_Float16)(u0.y * wscale),
                   (_Float16)(u0.z * wscale), (_Float16)(u0.w * wscale),
                   (_Float16)(u1.x * wscale), (_Float16)(u1.y * wscale),
                   (_Float16)(u1.z * wscale), (_Float16)(u1.w * wscale)};
        #pragma unroll
        for (int ns = 0; ns < 2; ++ns)
          acc[im][ns] = __builtin_amdgcn_mfma_f32_16x16x32_f16(a, bfr[ks][ns], acc[im][ns], 0, 0, 0);
      }
    }
  }

  #pragma unroll
  for (int im = 0; im < 3; ++im) {
    const int mt = mg * 3 + im;
    const int sec = mt >> 1;                    // 0=Q 1=K 2=V
    const int o_base = (mt & 1) * 64 + wv * 16 + quad * 4;
    const int hh = o_base >> 5, dd = o_base & 31;
    const int bh = b * HEADS + hh;
    if (sec < 2) {
      _Float16* dst = (sec == 0) ? Qw : Kw;
      #pragma unroll
      for (int ns = 0; ns < 2; ++ns) {
        int p = p0 + ns * 16 + lm;
        half4 v = {(_Float16)acc[im][ns][0], (_Float16)acc[im][ns][1],
                   (_Float16)acc[im][ns][2], (_Float16)acc[im][ns][3]};
        *(half4*)(dst + ((size_t)bh * HW + p) * DH + dd) = v;
      }
    } else {
      #pragma unroll
      for (int ns = 0; ns < 2; ++ns) {
        int p = p0 + ns * 16 + lm;
        #pragma unroll
        for (int r = 0; r < 4; ++r)
          Vtw[((size_t)bh * DH + dd + r) * HW + p] = (_Float16)acc[im][ns][r];
      }
    }
  }
}

// ---------------------------------------------------------------------------
// attn: unchanged from R11/R12 (32x32x16, split-K x2, both-hypothesis XOR
// keys, VALU lsum). ~62-64 us, conflicts 2.1M (2-way aliasing, free per
// m136) — LDS work concluded. grid (32, 16, 2) x 256.
// ---------------------------------------------------------------------------
__global__ __launch_bounds__(256) void attn(
    const _Float16* __restrict__ Qw, const _Float16* __restrict__ Kw,
    const _Float16* __restrict__ Vtw, float* __restrict__ Op,
    float* __restrict__ lp)
{
  __shared__ _Float16 ks[2][64][32];          // [phase][k][d]  8 KB
  __shared__ _Float16 vt[2][32][64];          // [phase][d][k]  8 KB

  const int bh = blockIdx.y, qt = blockIdx.x, z = blockIdx.z;
  const int tid = threadIdx.x;
  const int wv = tid >> 6, lane = tid & 63;
  const int l31 = lane & 31, hi = lane >> 5;

  const _Float16* qbase =
      Qw + ((size_t)bh * HW + qt * 128 + wv * 32 + l31) * DH + hi * 8;
  const half8 qb0 = *(const half8*)qbase;        // d = hi*8 + 0..7
  const half8 qb1 = *(const half8*)(qbase + 16); // d = 16 + hi*8 + 0..7

  const floatx16 shift16 = {-SHIFT2,-SHIFT2,-SHIFT2,-SHIFT2,
                            -SHIFT2,-SHIFT2,-SHIFT2,-SHIFT2,
                            -SHIFT2,-SHIFT2,-SHIFT2,-SHIFT2,
                            -SHIFT2,-SHIFT2,-SHIFT2,-SHIFT2};
  floatx16 oT = {0,0,0,0,0,0,0,0,0,0,0,0,0,0,0,0};
  float lsum = 0.0f;

  const _Float16* kbase = Kw  + (size_t)bh * HW * DH + (size_t)z * KHALF * DH;
  const _Float16* vbase = Vtw + (size_t)bh * DH * HW + (size_t)z * KHALF;
  const int kr = tid >> 2, kls = tid & 3;              // K logical slot
  const int vr = tid >> 3, vls = tid & 7;              // V logical slot
  const int kps = (kls ^ (((kr >> 1) ^ (kr >> 3)) & 3)) * 8;  // K phys col
  const int vps = (vls ^ ((vr ^ (vr >> 3)) & 7)) * 8;         // V phys col
  const int kc = kls * 8, vc = vls * 8;                // global offsets

  const int krk = ((l31 >> 1) ^ (l31 >> 3)) & 3;
  const int vrk = (l31 ^ (l31 >> 3)) & 7;

  half8 kA = *(const half8*)(kbase + (size_t)kr * DH + kc);
  half8 vA = *(const half8*)(vbase + (size_t)vr * HW + vc);
  *(half8*)&ks[0][kr][kps] = kA;
  *(half8*)&vt[0][vr][vps] = vA;
  kA = *(const half8*)(kbase + ((size_t)64 + kr) * DH + kc);
  vA = *(const half8*)(vbase + (size_t)vr * HW + 64 + vc);
  __syncthreads();

  for (int it = 0; it < NIT; ++it) {
    const int ph = it & 1, nx = ph ^ 1;

    half8 ka[2][2];
    half8 va[4];
    #pragma unroll
    for (int t = 0; t < 2; ++t)
      #pragma unroll
      for (int d = 0; d < 2; ++d)
        ka[t][d] = *(const half8*)&ks[ph][t * 32 + l31][((d * 2 + hi) ^ krk) * 8];
    #pragma unroll
    for (int k4 = 0; k4 < 4; ++k4)
      va[k4] = *(const half8*)&vt[ph][l31][((k4 * 2 + hi) ^ vrk) * 8];

    *(half8*)&ks[nx][kr][kps] = kA;
    *(half8*)&vt[nx][vr][vps] = vA;
    size_t koff = (size_t)(it + 2) * 64;
    if (koff > KHALF - 64) koff = KHALF - 64;
    kA = *(const half8*)(kbase + (koff + kr) * DH + kc);
    vA = *(const half8*)(vbase + (size_t)vr * HW + koff + vc);

    #pragma unroll
    for (int t = 0; t < 2; ++t) {
      floatx16 sT = __builtin_amdgcn_mfma_f32_32x32x16_f16(ka[t][0], qb0, shift16, 0, 0, 0);
      sT = __builtin_amdgcn_mfma_f32_32x32x16_f16(ka[t][1], qb1, sT, 0, 0, 0);
      float e[16];
      #pragma unroll
      for (int r = 0; r < 16; ++r) e[r] = __builtin_amdgcn_exp2f(sT[r]);
      lsum += (((e[0]+e[1])+(e[2]+e[3]))+((e[4]+e[5])+(e[6]+e[7])))
            + (((e[8]+e[9])+(e[10]+e[11]))+((e[12]+e[13])+(e[14]+e[15])));
      unsigned w0 = pkr(e[0],  e[1]),  w1 = pkr(e[2],  e[3]);
      unsigned w2 = pkr(e[4],  e[5]),  w3 = pkr(e[6],  e[7]);
      unsigned w4 = pkr(e[8],  e[9]),  w5 = pkr(e[10], e[11]);
      unsigned w6 = pkr(e[12], e[13]), w7 = pkr(e[14], e[15]);
      asm("v_permlane32_swap_b32 %0, %1" : "+v"(w0), "+v"(w2));
      asm("v_permlane32_swap_b32 %0, %1" : "+v"(w1), "+v"(w3));
      asm("v_permlane32_swap_b32 %0, %1" : "+v"(w4), "+v"(w6));
      asm("v_permlane32_swap_b32 %0, %1" : "+v"(w5), "+v"(w7));
      uint4v lo4 = {w0, w1, w2, w3}, hi4 = {w4, w5, w6, w7};
      half8 pbLo = __builtin_bit_cast(half8, lo4);
      half8 pbHi = __builtin_bit_cast(half8, hi4);
      oT = __builtin_amdgcn_mfma_f32_32x32x16_f16(va[2*t],     pbLo, oT, 0, 0, 0);
      oT = __builtin_amdgcn_mfma_f32_32x32x16_f16(va[2*t + 1], pbHi, oT, 0, 0, 0);
    }
    __syncthreads();
  }

  lsum += __shfl_xor(lsum, 32, 64);
  const int b = bh >> 2, hh = bh & 3;
  const int row = qt * 128 + wv * 32 + l31;
  float* obase = Op + ((size_t)z * 4 * HW + (size_t)b * HW + row) * HID + hh * DH;
  #pragma unroll
  for (int r0 = 0; r0 < 4; ++r0) {
    float4 v = {oT[4*r0], oT[4*r0+1], oT[4*r0+2], oT[4*r0+3]};
    *(float4*)(obase + 8 * r0 + 4 * hi) = v;
  }
  if (lane < 32)
    lp[(size_t)z * HEADS * 4 * HW + (size_t)bh * HW + row] = lsum;
}

// ---------------------------------------------------------------------------
// out_gemm v3 (unchanged from R12): A-fragments from L2-hot w_out, 16 B
// fragments hoisted once, 2 barriers. Split-K combine + normalize in
// B-staging. grid (2,256) x 256.
// ---------------------------------------------------------------------------
__global__ __launch_bounds__(256) void out_gemm(
    const float* __restrict__ wo, const float* __restrict__ Op,
    const float* __restrict__ lp, const float* __restrict__ bo,
    float* __restrict__ out)
{
  __shared__ _Float16 Bs[64][136];
  __shared__ float inv_l[64][4];
  const int mg = blockIdx.x, nt = blockIdx.y;
  const int b = nt >> 6, p0 = (nt & 63) * 64;
  const int tid = threadIdx.x;
  const int wv = tid >> 6, lane = tid & 63, lm = lane & 15, quad = lane >> 4;

  // combine row sums: inv_l[p][head] = 1/(l_z0 + l_z1)
  {
    const int p = tid >> 2, hh = tid & 3;
    const size_t qi = (size_t)(b * HEADS + hh) * HW + p0 + p;
    inv_l[p][hh] = 1.0f / (lp[qi] + lp[(size_t)HEADS * 4 * HW + qi]);
  }
  __syncthreads();   // inv_l ready

  const float* Bp0 = Op + ((size_t)b * HW + p0) * HID;          // z = 0
  const float* Bp1 = Bp0 + (size_t)4 * HW * HID;                // z = 1

  // stage combined B tile once
  #pragma unroll
  for (int i = 0; i < 4; ++i) {
    int ci = tid + i * 256;
    int r = ci >> 4, c8 = (ci & 15) * 8;
    const float* s0 = Bp0 + (size_t)r * HID + c8;
    const float* s1 = Bp1 + (size_t)r * HID + c8;
    float4 o0 = *(const float4*)(s0);
    float4 o1 = *(const float4*)(s0 + 4);
    float4 o2 = *(const float4*)(s1);
    float4 o3 = *(const float4*)(s1 + 4);
    const float sc = inv_l[r][c8 >> 5];   // 8 cols stay within one head
    half8 hb = {(_Float16)((o0.x + o2.x) * sc), (_Float16)((o0.y + o2.y) * sc),
                (_Float16)((o0.z + o2.z) * sc), (_Float16)((o0.w + o2.w) * sc),
                (_Float16)((o1.x + o3.x) * sc), (_Float16)((o1.y + o3.y) * sc),
                (_Float16)((o1.z + o3.z) * sc), (_Float16)((o1.w + o3.w) * sc)};
    *(half8*)&Bs[r][c8] = hb;
  }
  __syncthreads();   // Bs ready

  // hoist all 16 B fragments once; reused by both m-tiles
  half8 bfr[4][4];
  #pragma unroll
  for (int ks = 0; ks < 4; ++ks)
    #pragma unroll
    for (int ns = 0; ns < 4; ++ns)
      bfr[ks][ns] = *(const half8*)&Bs[ns * 16 + lm][ks * 32 + quad * 8];

  #pragma unroll
  for (int im = 0; im < 2; ++im) {
    const int mt = mg * 2 + im;
    const float* Ag = wo + (size_t)(mt * 64 + wv * 16 + lm) * HID;

    floatx4 acc[4] = {{0,0,0,0},{0,0,0,0},{0,0,0,0},{0,0,0,0}};
    #pragma unroll
    for (int ks = 0; ks < 4; ++ks) {
      const float* srcA = Ag + ks * 32 + quad * 8;
      float4 u0 = *(const float4*)(srcA);
      float4 u1 = *(const float4*)(srcA + 4);
      half8 a = {(_Float16)u0.x, (_Float16)u0.y, (_Float16)u0.z, (_Float16)u0.w,
                 (_Float16)u1.x, (_Float16)u1.y, (_Float16)u1.z, (_Float16)u1.w};
      #pragma unroll
      for (int ns = 0; ns < 4; ++ns)
        acc[ns] = __builtin_amdgcn_mfma_f32_16x16x32_f16(a, bfr[ks][ns], acc[ns], 0, 0, 0);
    }

    // direct stores: C[o][p], o = mt*64 + wv*16 + quad*4 + r, p = p0 + ns*16 + lm
    const int o_loc = wv * 16 + quad * 4;
    #pragma unroll
    for (int r = 0; r < 4; ++r) {
      const int o = mt * 64 + o_loc + r;
      const float bias = bo[o];
      float* dst = out + ((size_t)(b * CIN + o)) * HW + p0 + lm;
      #pragma unroll
      for (int ns = 0; ns < 4; ++ns)
        dst[ns * 16] = acc[ns][r] + bias;
    }
  }
}

// ---------------------------------------------------------------------------
extern "C" void kernel_launch(void* const* d_in, const int* in_sizes, int n_in,
                              void* d_out, int out_size, void* d_ws, size_t ws_size,
                              hipStream_t stream)
{
  const float* x     = (const float*)d_in[0];   // [4,256,64,64]
  const float* w_qkv = (const float*)d_in[1];   // [384,256]
  const float* w_out = (const float*)d_in[2];   // [256,128]
  const float* b_out = (const float*)d_in[3];   // [256]
  float* out = (float*)d_out;

  char* ws = (char*)d_ws;
  _Float16* Qw  = (_Float16*)(ws);               //  4 MB [bh][p][d], log2e-scaled
  _Float16* Kw  = (_Float16*)(ws + (4u  << 20)); //  4 MB [bh][p][d]
  _Float16* Vtw = (_Float16*)(ws + (8u  << 20)); //  4 MB [bh][d][p]
  float*    Op  = (float*)   (ws + (12u << 20)); // 16 MB [2][4][4096][128] f32
  float*    lp  = (float*)   (ws + (28u << 20)); // 0.5MB [2][16][4096] f32

  dim3 blk(256);
  qkv_fused<<<dim3(2, 512), blk, 0, stream>>>(w_qkv, x, Qw, Kw, Vtw);
  attn<<<dim3(32, 16, KSPLIT), blk, 0, stream>>>(Qw, Kw, Vtw, Op, lp);
  out_gemm<<<dim3(2, 256), blk, 0, stream>>>(w_out, Op, lp, b_out, out);
}

// Round 14
// 159.387 us; speedup vs baseline: 1.0270x; 1.0270x over previous
//
#include <hip/hip_runtime.h>
#include <hip/hip_fp16.h>

#define HEADS 4
#define DH    32
#define HW    4096
#define CIN   256
#define HID   128
#define KSPLIT 2
#define KHALF (HW / KSPLIT)
#define NIT   (KHALF / 64)

using half8    = __attribute__((ext_vector_type(8))) _Float16;
using half4    = __attribute__((ext_vector_type(4))) _Float16;
using half2v   = __attribute__((ext_vector_type(2))) _Float16;
using floatx4  = __attribute__((ext_vector_type(4))) float;
using floatx16 = __attribute__((ext_vector_type(16))) float;
using uint4v   = __attribute__((ext_vector_type(4))) unsigned;

// P = exp2(s_log2 - 3*log2e); log2(e) folded into Q pre-scale, shift folded
// into the S-MFMA C-initializer. Fixed shift (no running max) => split-K
// partials combine by pure addition.
#define SHIFT2 4.328085122666891f
#define WQSCALE 0.25508275947f   // 32^-0.5 * log2(e)

static __device__ __forceinline__ unsigned pkr(float a, float b) {
  return __builtin_bit_cast(unsigned, __builtin_amdgcn_cvt_pkrtz(a, b));
}

// ---------------------------------------------------------------------------
// qkv_fused v3 (REVERTED to R12 — R13's zero-LDS fragment gather cost +10 us;
// staged loads beat strided dword gathers even cache-hot). A-fragments from
// L2-hot w_qkv in registers; Bs fragments hoisted once per kq; 2 barriers/kq.
// grid (2,256) x 256.
// ---------------------------------------------------------------------------
__global__ __launch_bounds__(256) void qkv_fused(
    const float* __restrict__ w, const float* __restrict__ x,
    _Float16* __restrict__ Qw, _Float16* __restrict__ Kw,
    _Float16* __restrict__ Vtw)
{
  __shared__ float t[64][65];
  __shared__ _Float16 Bs[64][72];
  const int mg = blockIdx.x, nt = blockIdx.y;
  const int b = nt >> 6, p0 = (nt & 63) * 64;
  const int tid = threadIdx.x;
  const int wv = tid >> 6, lane = tid & 63, lm = lane & 15, quad = lane >> 4;

  const float* xb = x + (size_t)b * CIN * HW + p0;

  floatx4 acc[3][4] = {{{0,0,0,0},{0,0,0,0},{0,0,0,0},{0,0,0,0}},
                       {{0,0,0,0},{0,0,0,0},{0,0,0,0},{0,0,0,0}},
                       {{0,0,0,0},{0,0,0,0},{0,0,0,0},{0,0,0,0}}};

  for (int kq = 0; kq < 4; ++kq) {
    #pragma unroll
    for (int i = 0; i < 4; ++i) {
      int ci = tid + i * 256;
      int cc = ci >> 4, p4 = (ci & 15) * 4;
      *(float4*)&t[cc][p4] =
          *(const float4*)(xb + (size_t)(kq * 64 + cc) * HW + p4);
    }
    __syncthreads();   // t ready (also: prev bfr reads done -> Bs writable)
    #pragma unroll
    for (int i = 0; i < 2; ++i) {
      int idx = tid + i * 256;
      int p = idx >> 3, c0 = (idx & 7) * 8;
      half8 v;
      #pragma unroll
      for (int k = 0; k < 8; ++k) v[k] = (_Float16)t[c0 + k][p];
      *(half8*)&Bs[p][c0] = v;
    }
    __syncthreads();   // Bs ready

    // hoist all 8 B fragments once; reused by all 3 m-tiles
    half8 bfr[2][4];
    #pragma unroll
    for (int ks = 0; ks < 2; ++ks)
      #pragma unroll
      for (int ns = 0; ns < 4; ++ns)
        bfr[ks][ns] = *(const half8*)&Bs[ns * 16 + lm][ks * 32 + quad * 8];

    #pragma unroll
    for (int im = 0; im < 3; ++im) {
      const int mt = mg * 3 + im;
      const float wscale = (mt < 2) ? WQSCALE : 1.0f;
      const float* Ag = w + (size_t)(mt * 64 + wv * 16 + lm) * CIN + kq * 64;
      #pragma unroll
      for (int ks = 0; ks < 2; ++ks) {
        const float* srcA = Ag + ks * 32 + quad * 8;
        float4 u0 = *(const float4*)(srcA);
        float4 u1 = *(const float4*)(srcA + 4);
        half8 a = {(_Float16)(u0.x * wscale), (_Float16)(u0.y * wscale),
                   (_Float16)(u0.z * wscale), (_Float16)(u0.w * wscale),
                   (_Float16)(u1.x * wscale), (_Float16)(u1.y * wscale),
                   (_Float16)(u1.z * wscale), (_Float16)(u1.w * wscale)};
        #pragma unroll
        for (int ns = 0; ns < 4; ++ns)
          acc[im][ns] = __builtin_amdgcn_mfma_f32_16x16x32_f16(a, bfr[ks][ns], acc[im][ns], 0, 0, 0);
      }
    }
  }

  #pragma unroll
  for (int im = 0; im < 3; ++im) {
    const int mt = mg * 3 + im;
    const int sec = mt >> 1;                    // 0=Q 1=K 2=V
    const int o_base = (mt & 1) * 64 + wv * 16 + quad * 4;
    const int hh = o_base >> 5, dd = o_base & 31;
    const int bh = b * HEADS + hh;
    if (sec < 2) {
      _Float16* dst = (sec == 0) ? Qw : Kw;
      #pragma unroll
      for (int ns = 0; ns < 4; ++ns) {
        int p = p0 + ns * 16 + lm;
        half4 v = {(_Float16)acc[im][ns][0], (_Float16)acc[im][ns][1],
                   (_Float16)acc[im][ns][2], (_Float16)acc[im][ns][3]};
        *(half4*)(dst + ((size_t)bh * HW + p) * DH + dd) = v;
      }
    } else {
      #pragma unroll
      for (int ns = 0; ns < 4; ++ns) {
        int p = p0 + ns * 16 + lm;
        #pragma unroll
        for (int r = 0; r < 4; ++r)
          Vtw[((size_t)bh * DH + dd + r) * HW + p] = (_Float16)acc[im][ns][r];
      }
    }
  }
}

// ---------------------------------------------------------------------------
// attn: R11 structure; THIS ROUND — ILP reorder of the inner compute:
// (1) both t-groups' S-MFMA pairs issued back-to-back (matrix pipe works
//     while t=0's exps run on the trans pipe),
// (2) all 32 exps batched,
// (3) PV on SPLIT accumulators oT0/oT1 (breaks the 4-deep MFMA D->C chain),
//     merged by 16 f32 adds in the epilogue.
// Same arithmetic values; one f32 re-association (4x absmax margin).
// R12 counters showed ~700 VALU-busy cyc/wave-iter vs ~260 of issue work —
// the serial S->exp->pack->PV chain per t was the stall. grid (32,16,2)x256.
// ---------------------------------------------------------------------------
__global__ __launch_bounds__(256) void attn(
    const _Float16* __restrict__ Qw, const _Float16* __restrict__ Kw,
    const _Float16* __restrict__ Vtw, float* __restrict__ Op,
    float* __restrict__ lp)
{
  __shared__ _Float16 ks[2][64][32];          // [phase][k][d]  8 KB
  __shared__ _Float16 vt[2][32][64];          // [phase][d][k]  8 KB

  const int bh = blockIdx.y, qt = blockIdx.x, z = blockIdx.z;
  const int tid = threadIdx.x;
  const int wv = tid >> 6, lane = tid & 63;
  const int l31 = lane & 31, hi = lane >> 5;

  const _Float16* qbase =
      Qw + ((size_t)bh * HW + qt * 128 + wv * 32 + l31) * DH + hi * 8;
  const half8 qb0 = *(const half8*)qbase;        // d = hi*8 + 0..7
  const half8 qb1 = *(const half8*)(qbase + 16); // d = 16 + hi*8 + 0..7

  const floatx16 shift16 = {-SHIFT2,-SHIFT2,-SHIFT2,-SHIFT2,
                            -SHIFT2,-SHIFT2,-SHIFT2,-SHIFT2,
                            -SHIFT2,-SHIFT2,-SHIFT2,-SHIFT2,
                            -SHIFT2,-SHIFT2,-SHIFT2,-SHIFT2};
  floatx16 oT0 = {0,0,0,0,0,0,0,0,0,0,0,0,0,0,0,0};
  floatx16 oT1 = {0,0,0,0,0,0,0,0,0,0,0,0,0,0,0,0};
  float lsum = 0.0f;

  const _Float16* kbase = Kw  + (size_t)bh * HW * DH + (size_t)z * KHALF * DH;
  const _Float16* vbase = Vtw + (size_t)bh * DH * HW + (size_t)z * KHALF;
  const int kr = tid >> 2, kls = tid & 3;              // K logical slot
  const int vr = tid >> 3, vls = tid & 7;              // V logical slot
  const int kps = (kls ^ (((kr >> 1) ^ (kr >> 3)) & 3)) * 8;  // K phys col
  const int vps = (vls ^ ((vr ^ (vr >> 3)) & 7)) * 8;         // V phys col
  const int kc = kls * 8, vc = vls * 8;                // global offsets

  const int krk = ((l31 >> 1) ^ (l31 >> 3)) & 3;
  const int vrk = (l31 ^ (l31 >> 3)) & 7;

  half8 kA = *(const half8*)(kbase + (size_t)kr * DH + kc);
  half8 vA = *(const half8*)(vbase + (size_t)vr * HW + vc);
  *(half8*)&ks[0][kr][kps] = kA;
  *(half8*)&vt[0][vr][vps] = vA;
  kA = *(const half8*)(kbase + ((size_t)64 + kr) * DH + kc);
  vA = *(const half8*)(vbase + (size_t)vr * HW + 64 + vc);
  __syncthreads();

  for (int it = 0; it < NIT; ++it) {
    const int ph = it & 1, nx = ph ^ 1;

    half8 ka[2][2];
    half8 va[4];
    #pragma unroll
    for (int t = 0; t < 2; ++t)
      #pragma unroll
      for (int d = 0; d < 2; ++d)
        ka[t][d] = *(const half8*)&ks[ph][t * 32 + l31][((d * 2 + hi) ^ krk) * 8];
    #pragma unroll
    for (int k4 = 0; k4 < 4; ++k4)
      va[k4] = *(const half8*)&vt[ph][l31][((k4 * 2 + hi) ^ vrk) * 8];

    *(half8*)&ks[nx][kr][kps] = kA;
    *(half8*)&vt[nx][vr][vps] = vA;
    size_t koff = (size_t)(it + 2) * 64;
    if (koff > KHALF - 64) koff = KHALF - 64;
    kA = *(const half8*)(kbase + (koff + kr) * DH + kc);
    vA = *(const half8*)(vbase + (size_t)vr * HW + koff + vc);

    // --- both S-MFMA pairs first: matrix pipe fills while exps run ---
    floatx16 sT0 = __builtin_amdgcn_mfma_f32_32x32x16_f16(ka[0][0], qb0, shift16, 0, 0, 0);
    sT0 = __builtin_amdgcn_mfma_f32_32x32x16_f16(ka[0][1], qb1, sT0, 0, 0, 0);
    floatx16 sT1 = __builtin_amdgcn_mfma_f32_32x32x16_f16(ka[1][0], qb0, shift16, 0, 0, 0);
    sT1 = __builtin_amdgcn_mfma_f32_32x32x16_f16(ka[1][1], qb1, sT1, 0, 0, 0);

    // --- all 32 exps batched (trans pipe) ---
    float e0[16], e1[16];
    #pragma unroll
    for (int r = 0; r < 16; ++r) e0[r] = __builtin_amdgcn_exp2f(sT0[r]);
    #pragma unroll
    for (int r = 0; r < 16; ++r) e1[r] = __builtin_amdgcn_exp2f(sT1[r]);
    lsum += (((e0[0]+e0[1])+(e0[2]+e0[3]))+((e0[4]+e0[5])+(e0[6]+e0[7])))
          + (((e0[8]+e0[9])+(e0[10]+e0[11]))+((e0[12]+e0[13])+(e0[14]+e0[15])))
          + (((e1[0]+e1[1])+(e1[2]+e1[3]))+((e1[4]+e1[5])+(e1[6]+e1[7])))
          + (((e1[8]+e1[9])+(e1[10]+e1[11]))+((e1[12]+e1[13])+(e1[14]+e1[15])));

    // --- packs ---
    unsigned a0 = pkr(e0[0],  e0[1]),  a1 = pkr(e0[2],  e0[3]);
    unsigned a2 = pkr(e0[4],  e0[5]),  a3 = pkr(e0[6],  e0[7]);
    unsigned a4 = pkr(e0[8],  e0[9]),  a5 = pkr(e0[10], e0[11]);
    unsigned a6 = pkr(e0[12], e0[13]), a7 = pkr(e0[14], e0[15]);
    unsigned b0 = pkr(e1[0],  e1[1]),  b1 = pkr(e1[2],  e1[3]);
    unsigned b2 = pkr(e1[4],  e1[5]),  b3 = pkr(e1[6],  e1[7]);
    unsigned b4 = pkr(e1[8],  e1[9]),  b5 = pkr(e1[10], e1[11]);
    unsigned b6 = pkr(e1[12], e1[13]), b7 = pkr(e1[14], e1[15]);
    asm("v_permlane32_swap_b32 %0, %1" : "+v"(a0), "+v"(a2));
    asm("v_permlane32_swap_b32 %0, %1" : "+v"(a1), "+v"(a3));
    asm("v_permlane32_swap_b32 %0, %1" : "+v"(a4), "+v"(a6));
    asm("v_permlane32_swap_b32 %0, %1" : "+v"(a5), "+v"(a7));
    asm("v_permlane32_swap_b32 %0, %1" : "+v"(b0), "+v"(b2));
    asm("v_permlane32_swap_b32 %0, %1" : "+v"(b1), "+v"(b3));
    asm("v_permlane32_swap_b32 %0, %1" : "+v"(b4), "+v"(b6));
    asm("v_permlane32_swap_b32 %0, %1" : "+v"(b5), "+v"(b7));
    uint4v a_lo = {a0, a1, a2, a3}, a_hi = {a4, a5, a6, a7};
    uint4v b_lo = {b0, b1, b2, b3}, b_hi = {b4, b5, b6, b7};
    half8 p0Lo = __builtin_bit_cast(half8, a_lo);
    half8 p0Hi = __builtin_bit_cast(half8, a_hi);
    half8 p1Lo = __builtin_bit_cast(half8, b_lo);
    half8 p1Hi = __builtin_bit_cast(half8, b_hi);

    // --- PV on split accumulators: two independent 2-deep chains ---
    oT0 = __builtin_amdgcn_mfma_f32_32x32x16_f16(va[0], p0Lo, oT0, 0, 0, 0);
    oT1 = __builtin_amdgcn_mfma_f32_32x32x16_f16(va[2], p1Lo, oT1, 0, 0, 0);
    oT0 = __builtin_amdgcn_mfma_f32_32x32x16_f16(va[1], p0Hi, oT0, 0, 0, 0);
    oT1 = __builtin_amdgcn_mfma_f32_32x32x16_f16(va[3], p1Hi, oT1, 0, 0, 0);

    __syncthreads();
  }

  lsum += __shfl_xor(lsum, 32, 64);
  const int b = bh >> 2, hh = bh & 3;
  const int row = qt * 128 + wv * 32 + l31;
  float* obase = Op + ((size_t)z * 4 * HW + (size_t)b * HW + row) * HID + hh * DH;
  #pragma unroll
  for (int r0 = 0; r0 < 4; ++r0) {
    float4 v = {oT0[4*r0]   + oT1[4*r0],   oT0[4*r0+1] + oT1[4*r0+1],
                oT0[4*r0+2] + oT1[4*r0+2], oT0[4*r0+3] + oT1[4*r0+3]};
    *(float4*)(obase + 8 * r0 + 4 * hi) = v;
  }
  if (lane < 32)
    lp[(size_t)z * HEADS * 4 * HW + (size_t)bh * HW + row] = lsum;
}

// ---------------------------------------------------------------------------
// out_gemm v3 (unchanged from R12): A-fragments from L2-hot w_out, 16 B
// fragments hoisted once, 2 barriers. Split-K combine + normalize in
// B-staging. grid (2,256) x 256.
// ---------------------------------------------------------------------------
__global__ __launch_bounds__(256) void out_gemm(
    const float* __restrict__ wo, const float* __restrict__ Op,
    const float* __restrict__ lp, const float* __restrict__ bo,
    float* __restrict__ out)
{
  __shared__ _Float16 Bs[64][136];
  __shared__ float inv_l[64][4];
  const int mg = blockIdx.x, nt = blockIdx.y;
  const int b = nt >> 6, p0 = (nt & 63) * 64;
  const int tid = threadIdx.x;
  const int wv = tid >> 6, lane = tid & 63, lm = lane & 15, quad = lane >> 4;

  // combine row sums: inv_l[p][head] = 1/(l_z0 + l_z1)
  {
    const int p = tid >> 2, hh = tid & 3;
    const size_t qi = (size_t)(b * HEADS + hh) * HW + p0 + p;
    inv_l[p][hh] = 1.0f / (lp[qi] + lp[(size_t)HEADS * 4 * HW + qi]);
  }
  __syncthreads();   // inv_l ready

  const float* Bp0 = Op + ((size_t)b * HW + p0) * HID;          // z = 0
  const float* Bp1 = Bp0 + (size_t)4 * HW * HID;                // z = 1

  // stage combined B tile once
  #pragma unroll
  for (int i = 0; i < 4; ++i) {
    int ci = tid + i * 256;
    int r = ci >> 4, c8 = (ci & 15) * 8;
    const float* s0 = Bp0 + (size_t)r * HID + c8;
    const float* s1 = Bp1 + (size_t)r * HID + c8;
    float4 o0 = *(const float4*)(s0);
    float4 o1 = *(const float4*)(s0 + 4);
    float4 o2 = *(const float4*)(s1);
    float4 o3 = *(const float4*)(s1 + 4);
    const float sc = inv_l[r][c8 >> 5];   // 8 cols stay within one head
    half8 hb = {(_Float16)((o0.x + o2.x) * sc), (_Float16)((o0.y + o2.y) * sc),
                (_Float16)((o0.z + o2.z) * sc), (_Float16)((o0.w + o2.w) * sc),
                (_Float16)((o1.x + o3.x) * sc), (_Float16)((o1.y + o3.y) * sc),
                (_Float16)((o1.z + o3.z) * sc), (_Float16)((o1.w + o3.w) * sc)};
    *(half8*)&Bs[r][c8] = hb;
  }
  __syncthreads();   // Bs ready

  // hoist all 16 B fragments once; reused by both m-tiles
  half8 bfr[4][4];
  #pragma unroll
  for (int ks = 0; ks < 4; ++ks)
    #pragma unroll
    for (int ns = 0; ns < 4; ++ns)
      bfr[ks][ns] = *(const half8*)&Bs[ns * 16 + lm][ks * 32 + quad * 8];

  #pragma unroll
  for (int im = 0; im < 2; ++im) {
    const int mt = mg * 2 + im;
    const float* Ag = wo + (size_t)(mt * 64 + wv * 16 + lm) * HID;

    floatx4 acc[4] = {{0,0,0,0},{0,0,0,0},{0,0,0,0},{0,0,0,0}};
    #pragma unroll
    for (int ks = 0; ks < 4; ++ks) {
      const float* srcA = Ag + ks * 32 + quad * 8;
      float4 u0 = *(const float4*)(srcA);
      float4 u1 = *(const float4*)(srcA + 4);
      half8 a = {(_Float16)u0.x, (_Float16)u0.y, (_Float16)u0.z, (_Float16)u0.w,
                 (_Float16)u1.x, (_Float16)u1.y, (_Float16)u1.z, (_Float16)u1.w};
      #pragma unroll
      for (int ns = 0; ns < 4; ++ns)
        acc[ns] = __builtin_amdgcn_mfma_f32_16x16x32_f16(a, bfr[ks][ns], acc[ns], 0, 0, 0);
    }

    // direct stores: C[o][p], o = mt*64 + wv*16 + quad*4 + r, p = p0 + ns*16 + lm
    const int o_loc = wv * 16 + quad * 4;
    #pragma unroll
    for (int r = 0; r < 4; ++r) {
      const int o = mt * 64 + o_loc + r;
      const float bias = bo[o];
      float* dst = out + ((size_t)(b * CIN + o)) * HW + p0 + lm;
      #pragma unroll
      for (int ns = 0; ns < 4; ++ns)
        dst[ns * 16] = acc[ns][r] + bias;
    }
  }
}

// ---------------------------------------------------------------------------
extern "C" void kernel_launch(void* const* d_in, const int* in_sizes, int n_in,
                              void* d_out, int out_size, void* d_ws, size_t ws_size,
                              hipStream_t stream)
{
  const float* x     = (const float*)d_in[0];   // [4,256,64,64]
  const float* w_qkv = (const float*)d_in[1];   // [384,256]
  const float* w_out = (const float*)d_in[2];   // [256,128]
  const float* b_out = (const float*)d_in[3];   // [256]
  float* out = (float*)d_out;

  char* ws = (char*)d_ws;
  _Float16* Qw  = (_Float16*)(ws);               //  4 MB [bh][p][d], log2e-scaled
  _Float16* Kw  = (_Float16*)(ws + (4u  << 20)); //  4 MB [bh][p][d]
  _Float16* Vtw = (_Float16*)(ws + (8u  << 20)); //  4 MB [bh][d][p]
  float*    Op  = (float*)   (ws + (12u << 20)); // 16 MB [2][4][4096][128] f32
  float*    lp  = (float*)   (ws + (28u << 20)); // 0.5MB [2][16][4096] f32

  dim3 blk(256);
  qkv_fused<<<dim3(2, 256), blk, 0, stream>>>(w_qkv, x, Qw, Kw, Vtw);
  attn<<<dim3(32, 16, KSPLIT), blk, 0, stream>>>(Qw, Kw, Vtw, Op, lp);
  out_gemm<<<dim3(2, 256), blk, 0, stream>>>(w_out, Op, lp, b_out, out);
}

// Round 15
// 157.965 us; speedup vs baseline: 1.0362x; 1.0090x over previous
//
#include <hip/hip_runtime.h>
#include <hip/hip_fp16.h>

#define HEADS 4
#define DH    32
#define HW    4096
#define CIN   256
#define HID   128
#define KSPLIT 2
#define KHALF (HW / KSPLIT)
#define NIT   (KHALF / 64)

using half8    = __attribute__((ext_vector_type(8))) _Float16;
using half4    = __attribute__((ext_vector_type(4))) _Float16;
using half2v   = __attribute__((ext_vector_type(2))) _Float16;
using floatx4  = __attribute__((ext_vector_type(4))) float;
using floatx16 = __attribute__((ext_vector_type(16))) float;
using uint4v   = __attribute__((ext_vector_type(4))) unsigned;

// P = exp2(s_log2 - 3*log2e); log2(e) folded into Q pre-scale, shift folded
// into the S-MFMA C-initializer. Fixed shift (no running max) => split-K
// partials combine by pure addition.
#define SHIFT2 4.328085122666891f
#define WQSCALE 0.25508275947f   // 32^-0.5 * log2(e)

static __device__ __forceinline__ unsigned pkr(float a, float b) {
  return __builtin_bit_cast(unsigned, __builtin_amdgcn_cvt_pkrtz(a, b));
}

// ---------------------------------------------------------------------------
// qkv_fused v3 (R12): A-fragments in registers from L2-hot w_qkv; Bs
// fragments hoisted once per kq; 2 barriers/kq. grid (2,256) x 256.
// ---------------------------------------------------------------------------
__global__ __launch_bounds__(256) void qkv_fused(
    const float* __restrict__ w, const float* __restrict__ x,
    _Float16* __restrict__ Qw, _Float16* __restrict__ Kw,
    _Float16* __restrict__ Vtw)
{
  __shared__ float t[64][65];
  __shared__ _Float16 Bs[64][72];
  const int mg = blockIdx.x, nt = blockIdx.y;
  const int b = nt >> 6, p0 = (nt & 63) * 64;
  const int tid = threadIdx.x;
  const int wv = tid >> 6, lane = tid & 63, lm = lane & 15, quad = lane >> 4;

  const float* xb = x + (size_t)b * CIN * HW + p0;

  floatx4 acc[3][4] = {{{0,0,0,0},{0,0,0,0},{0,0,0,0},{0,0,0,0}},
                       {{0,0,0,0},{0,0,0,0},{0,0,0,0},{0,0,0,0}},
                       {{0,0,0,0},{0,0,0,0},{0,0,0,0},{0,0,0,0}}};

  for (int kq = 0; kq < 4; ++kq) {
    #pragma unroll
    for (int i = 0; i < 4; ++i) {
      int ci = tid + i * 256;
      int cc = ci >> 4, p4 = (ci & 15) * 4;
      *(float4*)&t[cc][p4] =
          *(const float4*)(xb + (size_t)(kq * 64 + cc) * HW + p4);
    }
    __syncthreads();   // t ready (also: prev bfr reads done -> Bs writable)
    #pragma unroll
    for (int i = 0; i < 2; ++i) {
      int idx = tid + i * 256;
      int p = idx >> 3, c0 = (idx & 7) * 8;
      half8 v;
      #pragma unroll
      for (int k = 0; k < 8; ++k) v[k] = (_Float16)t[c0 + k][p];
      *(half8*)&Bs[p][c0] = v;
    }
    __syncthreads();   // Bs ready

    // hoist all 8 B fragments once; reused by all 3 m-tiles
    half8 bfr[2][4];
    #pragma unroll
    for (int ks = 0; ks < 2; ++ks)
      #pragma unroll
      for (int ns = 0; ns < 4; ++ns)
        bfr[ks][ns] = *(const half8*)&Bs[ns * 16 + lm][ks * 32 + quad * 8];

    #pragma unroll
    for (int im = 0; im < 3; ++im) {
      const int mt = mg * 3 + im;
      const float wscale = (mt < 2) ? WQSCALE : 1.0f;
      const float* Ag = w + (size_t)(mt * 64 + wv * 16 + lm) * CIN + kq * 64;
      #pragma unroll
      for (int ks = 0; ks < 2; ++ks) {
        const float* srcA = Ag + ks * 32 + quad * 8;
        float4 u0 = *(const float4*)(srcA);
        float4 u1 = *(const float4*)(srcA + 4);
        half8 a = {(_Float16)(u0.x * wscale), (_Float16)(u0.y * wscale),
                   (_Float16)(u0.z * wscale), (_Float16)(u0.w * wscale),
                   (_Float16)(u1.x * wscale), (_Float16)(u1.y * wscale),
                   (_Float16)(u1.z * wscale), (_Float16)(u1.w * wscale)};
        #pragma unroll
        for (int ns = 0; ns < 4; ++ns)
          acc[im][ns] = __builtin_amdgcn_mfma_f32_16x16x32_f16(a, bfr[ks][ns], acc[im][ns], 0, 0, 0);
      }
    }
  }

  #pragma unroll
  for (int im = 0; im < 3; ++im) {
    const int mt = mg * 3 + im;
    const int sec = mt >> 1;                    // 0=Q 1=K 2=V
    const int o_base = (mt & 1) * 64 + wv * 16 + quad * 4;
    const int hh = o_base >> 5, dd = o_base & 31;
    const int bh = b * HEADS + hh;
    if (sec < 2) {
      _Float16* dst = (sec == 0) ? Qw : Kw;
      #pragma unroll
      for (int ns = 0; ns < 4; ++ns) {
        int p = p0 + ns * 16 + lm;
        half4 v = {(_Float16)acc[im][ns][0], (_Float16)acc[im][ns][1],
                   (_Float16)acc[im][ns][2], (_Float16)acc[im][ns][3]};
        *(half4*)(dst + ((size_t)bh * HW + p) * DH + dd) = v;
      }
    } else {
      #pragma unroll
      for (int ns = 0; ns < 4; ++ns) {
        int p = p0 + ns * 16 + lm;
        #pragma unroll
        for (int r = 0; r < 4; ++r)
          Vtw[((size_t)bh * DH + dd + r) * HW + p] = (_Float16)acc[im][ns][r];
      }
    }
  }
}

// ---------------------------------------------------------------------------
// attn: EXACT R12 structure (R14's ILP reorder regressed: +8 VGPR, occupancy
// 23->17%, +7 us — reverted). ONE change: O-partials stored as f16 (numerics:
// |O|<~30, f16 rel err 2^-11 enters the numerator of a normalized quotient
// -> ~5e-5 output error; lsum stays f32). Halves partial-store traffic.
// grid (32, 16, 2) x 256.
// ---------------------------------------------------------------------------
__global__ __launch_bounds__(256) void attn(
    const _Float16* __restrict__ Qw, const _Float16* __restrict__ Kw,
    const _Float16* __restrict__ Vtw, _Float16* __restrict__ Op,
    float* __restrict__ lp)
{
  __shared__ _Float16 ks[2][64][32];          // [phase][k][d]  8 KB
  __shared__ _Float16 vt[2][32][64];          // [phase][d][k]  8 KB

  const int bh = blockIdx.y, qt = blockIdx.x, z = blockIdx.z;
  const int tid = threadIdx.x;
  const int wv = tid >> 6, lane = tid & 63;
  const int l31 = lane & 31, hi = lane >> 5;

  const _Float16* qbase =
      Qw + ((size_t)bh * HW + qt * 128 + wv * 32 + l31) * DH + hi * 8;
  const half8 qb0 = *(const half8*)qbase;        // d = hi*8 + 0..7
  const half8 qb1 = *(const half8*)(qbase + 16); // d = 16 + hi*8 + 0..7

  const floatx16 shift16 = {-SHIFT2,-SHIFT2,-SHIFT2,-SHIFT2,
                            -SHIFT2,-SHIFT2,-SHIFT2,-SHIFT2,
                            -SHIFT2,-SHIFT2,-SHIFT2,-SHIFT2,
                            -SHIFT2,-SHIFT2,-SHIFT2,-SHIFT2};
  floatx16 oT = {0,0,0,0,0,0,0,0,0,0,0,0,0,0,0,0};
  float lsum = 0.0f;

  const _Float16* kbase = Kw  + (size_t)bh * HW * DH + (size_t)z * KHALF * DH;
  const _Float16* vbase = Vtw + (size_t)bh * DH * HW + (size_t)z * KHALF;
  const int kr = tid >> 2, kls = tid & 3;              // K logical slot
  const int vr = tid >> 3, vls = tid & 7;              // V logical slot
  const int kps = (kls ^ (((kr >> 1) ^ (kr >> 3)) & 3)) * 8;  // K phys col
  const int vps = (vls ^ ((vr ^ (vr >> 3)) & 7)) * 8;         // V phys col
  const int kc = kls * 8, vc = vls * 8;                // global offsets

  const int krk = ((l31 >> 1) ^ (l31 >> 3)) & 3;
  const int vrk = (l31 ^ (l31 >> 3)) & 7;

  half8 kA = *(const half8*)(kbase + (size_t)kr * DH + kc);
  half8 vA = *(const half8*)(vbase + (size_t)vr * HW + vc);
  *(half8*)&ks[0][kr][kps] = kA;
  *(half8*)&vt[0][vr][vps] = vA;
  kA = *(const half8*)(kbase + ((size_t)64 + kr) * DH + kc);
  vA = *(const half8*)(vbase + (size_t)vr * HW + 64 + vc);
  __syncthreads();

  for (int it = 0; it < NIT; ++it) {
    const int ph = it & 1, nx = ph ^ 1;

    half8 ka[2][2];
    half8 va[4];
    #pragma unroll
    for (int t = 0; t < 2; ++t)
      #pragma unroll
      for (int d = 0; d < 2; ++d)
        ka[t][d] = *(const half8*)&ks[ph][t * 32 + l31][((d * 2 + hi) ^ krk) * 8];
    #pragma unroll
    for (int k4 = 0; k4 < 4; ++k4)
      va[k4] = *(const half8*)&vt[ph][l31][((k4 * 2 + hi) ^ vrk) * 8];

    *(half8*)&ks[nx][kr][kps] = kA;
    *(half8*)&vt[nx][vr][vps] = vA;
    size_t koff = (size_t)(it + 2) * 64;
    if (koff > KHALF - 64) koff = KHALF - 64;
    kA = *(const half8*)(kbase + (koff + kr) * DH + kc);
    vA = *(const half8*)(vbase + (size_t)vr * HW + koff + vc);

    #pragma unroll
    for (int t = 0; t < 2; ++t) {
      floatx16 sT = __builtin_amdgcn_mfma_f32_32x32x16_f16(ka[t][0], qb0, shift16, 0, 0, 0);
      sT = __builtin_amdgcn_mfma_f32_32x32x16_f16(ka[t][1], qb1, sT, 0, 0, 0);
      float e[16];
      #pragma unroll
      for (int r = 0; r < 16; ++r) e[r] = __builtin_amdgcn_exp2f(sT[r]);
      lsum += (((e[0]+e[1])+(e[2]+e[3]))+((e[4]+e[5])+(e[6]+e[7])))
            + (((e[8]+e[9])+(e[10]+e[11]))+((e[12]+e[13])+(e[14]+e[15])));
      unsigned w0 = pkr(e[0],  e[1]),  w1 = pkr(e[2],  e[3]);
      unsigned w2 = pkr(e[4],  e[5]),  w3 = pkr(e[6],  e[7]);
      unsigned w4 = pkr(e[8],  e[9]),  w5 = pkr(e[10], e[11]);
      unsigned w6 = pkr(e[12], e[13]), w7 = pkr(e[14], e[15]);
      asm("v_permlane32_swap_b32 %0, %1" : "+v"(w0), "+v"(w2));
      asm("v_permlane32_swap_b32 %0, %1" : "+v"(w1), "+v"(w3));
      asm("v_permlane32_swap_b32 %0, %1" : "+v"(w4), "+v"(w6));
      asm("v_permlane32_swap_b32 %0, %1" : "+v"(w5), "+v"(w7));
      uint4v lo4 = {w0, w1, w2, w3}, hi4 = {w4, w5, w6, w7};
      half8 pbLo = __builtin_bit_cast(half8, lo4);
      half8 pbHi = __builtin_bit_cast(half8, hi4);
      oT = __builtin_amdgcn_mfma_f32_32x32x16_f16(va[2*t],     pbLo, oT, 0, 0, 0);
      oT = __builtin_amdgcn_mfma_f32_32x32x16_f16(va[2*t + 1], pbHi, oT, 0, 0, 0);
    }
    __syncthreads();
  }

  lsum += __shfl_xor(lsum, 32, 64);
  const int b = bh >> 2, hh = bh & 3;
  const int row = qt * 128 + wv * 32 + l31;
  _Float16* obase = Op + ((size_t)z * 4 * HW + (size_t)b * HW + row) * HID + hh * DH;
  #pragma unroll
  for (int r0 = 0; r0 < 4; ++r0) {
    half4 v = {(_Float16)oT[4*r0],   (_Float16)oT[4*r0+1],
               (_Float16)oT[4*r0+2], (_Float16)oT[4*r0+3]};
    *(half4*)(obase + 8 * r0 + 4 * hi) = v;   // d = 8*r0 + 4*hi + 0..3
  }
  if (lane < 32)
    lp[(size_t)z * HEADS * 4 * HW + (size_t)bh * HW + row] = lsum;
}

// ---------------------------------------------------------------------------
// out_gemm v3 (R12) with f16 O-partials: combine reads half8 pairs (16B,
// coalesced), adds in f32, normalizes, packs to Bs. A-fragments from L2-hot
// w_out; 16 B fragments hoisted once; 2 barriers. grid (2,256) x 256.
// ---------------------------------------------------------------------------
__global__ __launch_bounds__(256) void out_gemm(
    const float* __restrict__ wo, const _Float16* __restrict__ Op,
    const float* __restrict__ lp, const float* __restrict__ bo,
    float* __restrict__ out)
{
  __shared__ _Float16 Bs[64][136];
  __shared__ float inv_l[64][4];
  const int mg = blockIdx.x, nt = blockIdx.y;
  const int b = nt >> 6, p0 = (nt & 63) * 64;
  const int tid = threadIdx.x;
  const int wv = tid >> 6, lane = tid & 63, lm = lane & 15, quad = lane >> 4;

  // combine row sums: inv_l[p][head] = 1/(l_z0 + l_z1)
  {
    const int p = tid >> 2, hh = tid & 3;
    const size_t qi = (size_t)(b * HEADS + hh) * HW + p0 + p;
    inv_l[p][hh] = 1.0f / (lp[qi] + lp[(size_t)HEADS * 4 * HW + qi]);
  }
  __syncthreads();   // inv_l ready

  const _Float16* Bp0 = Op + ((size_t)b * HW + p0) * HID;       // z = 0
  const _Float16* Bp1 = Bp0 + (size_t)4 * HW * HID;             // z = 1

  // stage combined B tile once
  #pragma unroll
  for (int i = 0; i < 4; ++i) {
    int ci = tid + i * 256;
    int r = ci >> 4, c8 = (ci & 15) * 8;
    half8 h0 = *(const half8*)(Bp0 + (size_t)r * HID + c8);
    half8 h1 = *(const half8*)(Bp1 + (size_t)r * HID + c8);
    const float sc = inv_l[r][c8 >> 5];   // 8 cols stay within one head
    half8 hb;
    #pragma unroll
    for (int j = 0; j < 8; ++j)
      hb[j] = (_Float16)(((float)h0[j] + (float)h1[j]) * sc);
    *(half8*)&Bs[r][c8] = hb;
  }
  __syncthreads();   // Bs ready

  // hoist all 16 B fragments once; reused by both m-tiles
  half8 bfr[4][4];
  #pragma unroll
  for (int ks = 0; ks < 4; ++ks)
    #pragma unroll
    for (int ns = 0; ns < 4; ++ns)
      bfr[ks][ns] = *(const half8*)&Bs[ns * 16 + lm][ks * 32 + quad * 8];

  #pragma unroll
  for (int im = 0; im < 2; ++im) {
    const int mt = mg * 2 + im;
    const float* Ag = wo + (size_t)(mt * 64 + wv * 16 + lm) * HID;

    floatx4 acc[4] = {{0,0,0,0},{0,0,0,0},{0,0,0,0},{0,0,0,0}};
    #pragma unroll
    for (int ks = 0; ks < 4; ++ks) {
      const float* srcA = Ag + ks * 32 + quad * 8;
      float4 u0 = *(const float4*)(srcA);
      float4 u1 = *(const float4*)(srcA + 4);
      half8 a = {(_Float16)u0.x, (_Float16)u0.y, (_Float16)u0.z, (_Float16)u0.w,
                 (_Float16)u1.x, (_Float16)u1.y, (_Float16)u1.z, (_Float16)u1.w};
      #pragma unroll
      for (int ns = 0; ns < 4; ++ns)
        acc[ns] = __builtin_amdgcn_mfma_f32_16x16x32_f16(a, bfr[ks][ns], acc[ns], 0, 0, 0);
    }

    // direct stores: C[o][p], o = mt*64 + wv*16 + quad*4 + r, p = p0 + ns*16 + lm
    const int o_loc = wv * 16 + quad * 4;
    #pragma unroll
    for (int r = 0; r < 4; ++r) {
      const int o = mt * 64 + o_loc + r;
      const float bias = bo[o];
      float* dst = out + ((size_t)(b * CIN + o)) * HW + p0 + lm;
      #pragma unroll
      for (int ns = 0; ns < 4; ++ns)
        dst[ns * 16] = acc[ns][r] + bias;
    }
  }
}

// ---------------------------------------------------------------------------
extern "C" void kernel_launch(void* const* d_in, const int* in_sizes, int n_in,
                              void* d_out, int out_size, void* d_ws, size_t ws_size,
                              hipStream_t stream)
{
  const float* x     = (const float*)d_in[0];   // [4,256,64,64]
  const float* w_qkv = (const float*)d_in[1];   // [384,256]
  const float* w_out = (const float*)d_in[2];   // [256,128]
  const float* b_out = (const float*)d_in[3];   // [256]
  float* out = (float*)d_out;

  char* ws = (char*)d_ws;
  _Float16* Qw  = (_Float16*)(ws);               //  4 MB [bh][p][d], log2e-scaled
  _Float16* Kw  = (_Float16*)(ws + (4u  << 20)); //  4 MB [bh][p][d]
  _Float16* Vtw = (_Float16*)(ws + (8u  << 20)); //  4 MB [bh][d][p]
  _Float16* Op  = (_Float16*)(ws + (12u << 20)); //  8 MB [2][4][4096][128] f16
  float*    lp  = (float*)   (ws + (20u << 20)); // 0.5MB [2][16][4096] f32

  dim3 blk(256);
  qkv_fused<<<dim3(2, 256), blk, 0, stream>>>(w_qkv, x, Qw, Kw, Vtw);
  attn<<<dim3(32, 16, KSPLIT), blk, 0, stream>>>(Qw, Kw, Vtw, Op, lp);
  out_gemm<<<dim3(2, 256), blk, 0, stream>>>(w_out, Op, lp, b_out, out);
}

// Round 16
// 157.631 us; speedup vs baseline: 1.0384x; 1.0021x over previous
//
#include <hip/hip_runtime.h>
#include <hip/hip_fp16.h>

#define HEADS 4
#define DH    32
#define HW    4096
#define CIN   256
#define HID   128
#define KSPLIT 2
#define KHALF (HW / KSPLIT)
#define NIT   (KHALF / 64)

using half8    = __attribute__((ext_vector_type(8))) _Float16;
using half4    = __attribute__((ext_vector_type(4))) _Float16;
using half2v   = __attribute__((ext_vector_type(2))) _Float16;
using floatx4  = __attribute__((ext_vector_type(4))) float;
using floatx16 = __attribute__((ext_vector_type(16))) float;
using uint4v   = __attribute__((ext_vector_type(4))) unsigned;

// P = exp2(s_log2 - 3*log2e); log2(e) folded into Q pre-scale, shift folded
// into the S-MFMA C-initializer. Fixed shift (no running max) => split-K
// partials combine by pure addition.
#define SHIFT2 4.328085122666891f
#define WQSCALE 0.25508275947f   // 32^-0.5 * log2(e)

static __device__ __forceinline__ unsigned pkr(float a, float b) {
  return __builtin_bit_cast(unsigned, __builtin_amdgcn_cvt_pkrtz(a, b));
}

// ---------------------------------------------------------------------------
// qkv_fused v3 (R12, exact): A-fragments in registers from L2-hot w_qkv; Bs
// fragments hoisted once per kq; 2 barriers/kq. grid (2,256) x 256.
// ---------------------------------------------------------------------------
__global__ __launch_bounds__(256) void qkv_fused(
    const float* __restrict__ w, const float* __restrict__ x,
    _Float16* __restrict__ Qw, _Float16* __restrict__ Kw,
    _Float16* __restrict__ Vtw)
{
  __shared__ float t[64][65];
  __shared__ _Float16 Bs[64][72];
  const int mg = blockIdx.x, nt = blockIdx.y;
  const int b = nt >> 6, p0 = (nt & 63) * 64;
  const int tid = threadIdx.x;
  const int wv = tid >> 6, lane = tid & 63, lm = lane & 15, quad = lane >> 4;

  const float* xb = x + (size_t)b * CIN * HW + p0;

  floatx4 acc[3][4] = {{{0,0,0,0},{0,0,0,0},{0,0,0,0},{0,0,0,0}},
                       {{0,0,0,0},{0,0,0,0},{0,0,0,0},{0,0,0,0}},
                       {{0,0,0,0},{0,0,0,0},{0,0,0,0},{0,0,0,0}}};

  for (int kq = 0; kq < 4; ++kq) {
    #pragma unroll
    for (int i = 0; i < 4; ++i) {
      int ci = tid + i * 256;
      int cc = ci >> 4, p4 = (ci & 15) * 4;
      *(float4*)&t[cc][p4] =
          *(const float4*)(xb + (size_t)(kq * 64 + cc) * HW + p4);
    }
    __syncthreads();   // t ready (also: prev bfr reads done -> Bs writable)
    #pragma unroll
    for (int i = 0; i < 2; ++i) {
      int idx = tid + i * 256;
      int p = idx >> 3, c0 = (idx & 7) * 8;
      half8 v;
      #pragma unroll
      for (int k = 0; k < 8; ++k) v[k] = (_Float16)t[c0 + k][p];
      *(half8*)&Bs[p][c0] = v;
    }
    __syncthreads();   // Bs ready

    // hoist all 8 B fragments once; reused by all 3 m-tiles
    half8 bfr[2][4];
    #pragma unroll
    for (int ks = 0; ks < 2; ++ks)
      #pragma unroll
      for (int ns = 0; ns < 4; ++ns)
        bfr[ks][ns] = *(const half8*)&Bs[ns * 16 + lm][ks * 32 + quad * 8];

    #pragma unroll
    for (int im = 0; im < 3; ++im) {
      const int mt = mg * 3 + im;
      const float wscale = (mt < 2) ? WQSCALE : 1.0f;
      const float* Ag = w + (size_t)(mt * 64 + wv * 16 + lm) * CIN + kq * 64;
      #pragma unroll
      for (int ks = 0; ks < 2; ++ks) {
        const float* srcA = Ag + ks * 32 + quad * 8;
        float4 u0 = *(const float4*)(srcA);
        float4 u1 = *(const float4*)(srcA + 4);
        half8 a = {(_Float16)(u0.x * wscale), (_Float16)(u0.y * wscale),
                   (_Float16)(u0.z * wscale), (_Float16)(u0.w * wscale),
                   (_Float16)(u1.x * wscale), (_Float16)(u1.y * wscale),
                   (_Float16)(u1.z * wscale), (_Float16)(u1.w * wscale)};
        #pragma unroll
        for (int ns = 0; ns < 4; ++ns)
          acc[im][ns] = __builtin_amdgcn_mfma_f32_16x16x32_f16(a, bfr[ks][ns], acc[im][ns], 0, 0, 0);
      }
    }
  }

  #pragma unroll
  for (int im = 0; im < 3; ++im) {
    const int mt = mg * 3 + im;
    const int sec = mt >> 1;                    // 0=Q 1=K 2=V
    const int o_base = (mt & 1) * 64 + wv * 16 + quad * 4;
    const int hh = o_base >> 5, dd = o_base & 31;
    const int bh = b * HEADS + hh;
    if (sec < 2) {
      _Float16* dst = (sec == 0) ? Qw : Kw;
      #pragma unroll
      for (int ns = 0; ns < 4; ++ns) {
        int p = p0 + ns * 16 + lm;
        half4 v = {(_Float16)acc[im][ns][0], (_Float16)acc[im][ns][1],
                   (_Float16)acc[im][ns][2], (_Float16)acc[im][ns][3]};
        *(half4*)(dst + ((size_t)bh * HW + p) * DH + dd) = v;
      }
    } else {
      #pragma unroll
      for (int ns = 0; ns < 4; ++ns) {
        int p = p0 + ns * 16 + lm;
        #pragma unroll
        for (int r = 0; r < 4; ++r)
          Vtw[((size_t)bh * DH + dd + r) * HW + p] = (_Float16)acc[im][ns][r];
      }
    }
  }
}

// ---------------------------------------------------------------------------
// attn: EXACT R12 (f32 partials — R15's f16 epilogue pack cost +9 us,
// reverted). 32x32x16 dataflow, split-K x2, both-hypothesis XOR keys,
// VALU lsum. grid (32, 16, 2) x 256.
// ---------------------------------------------------------------------------
__global__ __launch_bounds__(256) void attn(
    const _Float16* __restrict__ Qw, const _Float16* __restrict__ Kw,
    const _Float16* __restrict__ Vtw, float* __restrict__ Op,
    float* __restrict__ lp)
{
  __shared__ _Float16 ks[2][64][32];          // [phase][k][d]  8 KB
  __shared__ _Float16 vt[2][32][64];          // [phase][d][k]  8 KB

  const int bh = blockIdx.y, qt = blockIdx.x, z = blockIdx.z;
  const int tid = threadIdx.x;
  const int wv = tid >> 6, lane = tid & 63;
  const int l31 = lane & 31, hi = lane >> 5;

  const _Float16* qbase =
      Qw + ((size_t)bh * HW + qt * 128 + wv * 32 + l31) * DH + hi * 8;
  const half8 qb0 = *(const half8*)qbase;        // d = hi*8 + 0..7
  const half8 qb1 = *(const half8*)(qbase + 16); // d = 16 + hi*8 + 0..7

  const floatx16 shift16 = {-SHIFT2,-SHIFT2,-SHIFT2,-SHIFT2,
                            -SHIFT2,-SHIFT2,-SHIFT2,-SHIFT2,
                            -SHIFT2,-SHIFT2,-SHIFT2,-SHIFT2,
                            -SHIFT2,-SHIFT2,-SHIFT2,-SHIFT2};
  floatx16 oT = {0,0,0,0,0,0,0,0,0,0,0,0,0,0,0,0};
  float lsum = 0.0f;

  const _Float16* kbase = Kw  + (size_t)bh * HW * DH + (size_t)z * KHALF * DH;
  const _Float16* vbase = Vtw + (size_t)bh * DH * HW + (size_t)z * KHALF;
  const int kr = tid >> 2, kls = tid & 3;              // K logical slot
  const int vr = tid >> 3, vls = tid & 7;              // V logical slot
  const int kps = (kls ^ (((kr >> 1) ^ (kr >> 3)) & 3)) * 8;  // K phys col
  const int vps = (vls ^ ((vr ^ (vr >> 3)) & 7)) * 8;         // V phys col
  const int kc = kls * 8, vc = vls * 8;                // global offsets

  const int krk = ((l31 >> 1) ^ (l31 >> 3)) & 3;
  const int vrk = (l31 ^ (l31 >> 3)) & 7;

  half8 kA = *(const half8*)(kbase + (size_t)kr * DH + kc);
  half8 vA = *(const half8*)(vbase + (size_t)vr * HW + vc);
  *(half8*)&ks[0][kr][kps] = kA;
  *(half8*)&vt[0][vr][vps] = vA;
  kA = *(const half8*)(kbase + ((size_t)64 + kr) * DH + kc);
  vA = *(const half8*)(vbase + (size_t)vr * HW + 64 + vc);
  __syncthreads();

  for (int it = 0; it < NIT; ++it) {
    const int ph = it & 1, nx = ph ^ 1;

    half8 ka[2][2];
    half8 va[4];
    #pragma unroll
    for (int t = 0; t < 2; ++t)
      #pragma unroll
      for (int d = 0; d < 2; ++d)
        ka[t][d] = *(const half8*)&ks[ph][t * 32 + l31][((d * 2 + hi) ^ krk) * 8];
    #pragma unroll
    for (int k4 = 0; k4 < 4; ++k4)
      va[k4] = *(const half8*)&vt[ph][l31][((k4 * 2 + hi) ^ vrk) * 8];

    *(half8*)&ks[nx][kr][kps] = kA;
    *(half8*)&vt[nx][vr][vps] = vA;
    size_t koff = (size_t)(it + 2) * 64;
    if (koff > KHALF - 64) koff = KHALF - 64;
    kA = *(const half8*)(kbase + (koff + kr) * DH + kc);
    vA = *(const half8*)(vbase + (size_t)vr * HW + koff + vc);

    #pragma unroll
    for (int t = 0; t < 2; ++t) {
      floatx16 sT = __builtin_amdgcn_mfma_f32_32x32x16_f16(ka[t][0], qb0, shift16, 0, 0, 0);
      sT = __builtin_amdgcn_mfma_f32_32x32x16_f16(ka[t][1], qb1, sT, 0, 0, 0);
      float e[16];
      #pragma unroll
      for (int r = 0; r < 16; ++r) e[r] = __builtin_amdgcn_exp2f(sT[r]);
      lsum += (((e[0]+e[1])+(e[2]+e[3]))+((e[4]+e[5])+(e[6]+e[7])))
            + (((e[8]+e[9])+(e[10]+e[11]))+((e[12]+e[13])+(e[14]+e[15])));
      unsigned w0 = pkr(e[0],  e[1]),  w1 = pkr(e[2],  e[3]);
      unsigned w2 = pkr(e[4],  e[5]),  w3 = pkr(e[6],  e[7]);
      unsigned w4 = pkr(e[8],  e[9]),  w5 = pkr(e[10], e[11]);
      unsigned w6 = pkr(e[12], e[13]), w7 = pkr(e[14], e[15]);
      asm("v_permlane32_swap_b32 %0, %1" : "+v"(w0), "+v"(w2));
      asm("v_permlane32_swap_b32 %0, %1" : "+v"(w1), "+v"(w3));
      asm("v_permlane32_swap_b32 %0, %1" : "+v"(w4), "+v"(w6));
      asm("v_permlane32_swap_b32 %0, %1" : "+v"(w5), "+v"(w7));
      uint4v lo4 = {w0, w1, w2, w3}, hi4 = {w4, w5, w6, w7};
      half8 pbLo = __builtin_bit_cast(half8, lo4);
      half8 pbHi = __builtin_bit_cast(half8, hi4);
      oT = __builtin_amdgcn_mfma_f32_32x32x16_f16(va[2*t],     pbLo, oT, 0, 0, 0);
      oT = __builtin_amdgcn_mfma_f32_32x32x16_f16(va[2*t + 1], pbHi, oT, 0, 0, 0);
    }
    __syncthreads();
  }

  lsum += __shfl_xor(lsum, 32, 64);
  const int b = bh >> 2, hh = bh & 3;
  const int row = qt * 128 + wv * 32 + l31;
  float* obase = Op + ((size_t)z * 4 * HW + (size_t)b * HW + row) * HID + hh * DH;
  #pragma unroll
  for (int r0 = 0; r0 < 4; ++r0) {
    float4 v = {oT[4*r0], oT[4*r0+1], oT[4*r0+2], oT[4*r0+3]};
    *(float4*)(obase + 8 * r0 + 4 * hi) = v;
  }
  if (lane < 32)
    lp[(size_t)z * HEADS * 4 * HW + (size_t)bh * HW + row] = lsum;
}

// ---------------------------------------------------------------------------
// out_gemm v4: THIS ROUND — n-tile 64 -> 32 pixels. grid (2,512) = 1024
// blocks = 4 blocks/CU (was 512 = 2/CU; R2->R3 showed the 2->4 step is
// worth ~7% when per-block work halves on a latency-bound kernel). LDS
// 36 -> 9.2 KB; B-fragment hoist 16 -> 8 regs. Combine + A-from-global
// structure unchanged from R12.
// ---------------------------------------------------------------------------
__global__ __launch_bounds__(256) void out_gemm(
    const float* __restrict__ wo, const float* __restrict__ Op,
    const float* __restrict__ lp, const float* __restrict__ bo,
    float* __restrict__ out)
{
  __shared__ _Float16 Bs[32][136];
  __shared__ float inv_l[32][4];
  const int mg = blockIdx.x, nt = blockIdx.y;
  const int b = nt >> 7, p0 = (nt & 127) * 32;
  const int tid = threadIdx.x;
  const int wv = tid >> 6, lane = tid & 63, lm = lane & 15, quad = lane >> 4;

  // combine row sums: inv_l[p][head] = 1/(l_z0 + l_z1), 128 threads
  if (tid < 128) {
    const int p = tid >> 2, hh = tid & 3;
    const size_t qi = (size_t)(b * HEADS + hh) * HW + p0 + p;
    inv_l[p][hh] = 1.0f / (lp[qi] + lp[(size_t)HEADS * 4 * HW + qi]);
  }
  __syncthreads();   // inv_l ready

  const float* Bp0 = Op + ((size_t)b * HW + p0) * HID;          // z = 0
  const float* Bp1 = Bp0 + (size_t)4 * HW * HID;                // z = 1

  // stage combined B tile once (32 rows x 128 cols, 512 half8-slots)
  #pragma unroll
  for (int i = 0; i < 2; ++i) {
    int ci = tid + i * 256;
    int r = ci >> 4, c8 = (ci & 15) * 8;
    const float* s0 = Bp0 + (size_t)r * HID + c8;
    const float* s1 = Bp1 + (size_t)r * HID + c8;
    float4 o0 = *(const float4*)(s0);
    float4 o1 = *(const float4*)(s0 + 4);
    float4 o2 = *(const float4*)(s1);
    float4 o3 = *(const float4*)(s1 + 4);
    const float sc = inv_l[r][c8 >> 5];   // 8 cols stay within one head
    half8 hb = {(_Float16)((o0.x + o2.x) * sc), (_Float16)((o0.y + o2.y) * sc),
                (_Float16)((o0.z + o2.z) * sc), (_Float16)((o0.w + o2.w) * sc),
                (_Float16)((o1.x + o3.x) * sc), (_Float16)((o1.y + o3.y) * sc),
                (_Float16)((o1.z + o3.z) * sc), (_Float16)((o1.w + o3.w) * sc)};
    *(half8*)&Bs[r][c8] = hb;
  }
  __syncthreads();   // Bs ready

  // hoist all 8 B fragments once; reused by both m-tiles
  half8 bfr[4][2];
  #pragma unroll
  for (int ks = 0; ks < 4; ++ks)
    #pragma unroll
    for (int ns = 0; ns < 2; ++ns)
      bfr[ks][ns] = *(const half8*)&Bs[ns * 16 + lm][ks * 32 + quad * 8];

  #pragma unroll
  for (int im = 0; im < 2; ++im) {
    const int mt = mg * 2 + im;
    const float* Ag = wo + (size_t)(mt * 64 + wv * 16 + lm) * HID;

    floatx4 acc[2] = {{0,0,0,0},{0,0,0,0}};
    #pragma unroll
    for (int ks = 0; ks < 4; ++ks) {
      const float* srcA = Ag + ks * 32 + quad * 8;
      float4 u0 = *(const float4*)(srcA);
      float4 u1 = *(const float4*)(srcA + 4);
      half8 a = {(_Float16)u0.x, (_Float16)u0.y, (_Float16)u0.z, (_Float16)u0.w,
                 (_Float16)u1.x, (_Float16)u1.y, (_Float16)u1.z, (_Float16)u1.w};
      #pragma unroll
      for (int ns = 0; ns < 2; ++ns)
        acc[ns] = __builtin_amdgcn_mfma_f32_16x16x32_f16(a, bfr[ks][ns], acc[ns], 0, 0, 0);
    }

    // direct stores: C[o][p], o = mt*64 + wv*16 + quad*4 + r, p = p0 + ns*16 + lm
    const int o_loc = wv * 16 + quad * 4;
    #pragma unroll
    for (int r = 0; r < 4; ++r) {
      const int o = mt * 64 + o_loc + r;
      const float bias = bo[o];
      float* dst = out + ((size_t)(b * CIN + o)) * HW + p0 + lm;
      #pragma unroll
      for (int ns = 0; ns < 2; ++ns)
        dst[ns * 16] = acc[ns][r] + bias;
    }
  }
}

// ---------------------------------------------------------------------------
extern "C" void kernel_launch(void* const* d_in, const int* in_sizes, int n_in,
                              void* d_out, int out_size, void* d_ws, size_t ws_size,
                              hipStream_t stream)
{
  const float* x     = (const float*)d_in[0];   // [4,256,64,64]
  const float* w_qkv = (const float*)d_in[1];   // [384,256]
  const float* w_out = (const float*)d_in[2];   // [256,128]
  const float* b_out = (const float*)d_in[3];   // [256]
  float* out = (float*)d_out;

  char* ws = (char*)d_ws;
  _Float16* Qw  = (_Float16*)(ws);               //  4 MB [bh][p][d], log2e-scaled
  _Float16* Kw  = (_Float16*)(ws + (4u  << 20)); //  4 MB [bh][p][d]
  _Float16* Vtw = (_Float16*)(ws + (8u  << 20)); //  4 MB [bh][d][p]
  float*    Op  = (float*)   (ws + (12u << 20)); // 16 MB [2][4][4096][128] f32
  float*    lp  = (float*)   (ws + (28u << 20)); // 0.5MB [2][16][4096] f32

  dim3 blk(256);
  qkv_fused<<<dim3(2, 256), blk, 0, stream>>>(w_qkv, x, Qw, Kw, Vtw);
  attn<<<dim3(32, 16, KSPLIT), blk, 0, stream>>>(Qw, Kw, Vtw, Op, lp);
  out_gemm<<<dim3(2, 512), blk, 0, stream>>>(w_out, Op, lp, b_out, out);
}